// Round 2
// baseline (242.254 us; speedup 1.0000x reference)
//
#include <hip/hip_runtime.h>
#include <stdint.h>

typedef unsigned short u16;
typedef short bf16x8 __attribute__((ext_vector_type(8)));
typedef float f32x4 __attribute__((ext_vector_type(4)));

#define NIB 32
#define NOB 32
#define ABI 8
#define BSZ 128
#define INF 4096
#define OUTF 4096
#define LRK 64
#define NROWS 8192
#define KTOT 1088   // 8*128 sparse + 64 lowrank
#define BM 256
#define BN 128
#define BK 64
#define NKT 17      // 16 xb K-tiles + 1 hb tail tile

__device__ __forceinline__ u16 f2bf(float f) {
    uint32_t u = __float_as_uint(f);
    u += 0x7fffu + ((u >> 16) & 1u);
    return (u16)(u >> 16);
}

__device__ __forceinline__ void async16(const u16* g, u16* l) {
    __builtin_amdgcn_global_load_lds(
        (const __attribute__((address_space(1))) uint32_t*)g,
        (__attribute__((address_space(3))) uint32_t*)l, 16, 0, 0);
}

#define FENCE() asm volatile("" ::: "memory")
#define BAR() do { FENCE(); __builtin_amdgcn_s_barrier(); FENCE(); } while (0)

// ---------------------------------------------------------------------------
// Kernel 1: pack weights. Wbt[o][c][k] bf16, k-contiguous.
// k<1024: j=k>>7,b=k&127, i=(o-7+j)%32, a=7-j -> weight[((i*128+b)*8+a)*128+c]
// k>=1024: r=k-1024 -> L2[(o*128+c)*64+r].  L1b: f32->bf16 copy of L1.
// ---------------------------------------------------------------------------
__global__ __launch_bounds__(256) void gm_prep(
        const float* __restrict__ W, const float* __restrict__ L1,
        const float* __restrict__ L2,
        u16* __restrict__ Wbt, u16* __restrict__ L1b) {
    int idx = blockIdx.x * 256 + threadIdx.x;
    const int totW = NOB * BSZ * KTOT;          // 4456448
    if (idx < totW) {
        int o   = idx / (BSZ * KTOT);
        int rem = idx % (BSZ * KTOT);
        int c   = rem / KTOT;
        int k   = rem % KTOT;
        float v;
        if (k < 1024) {
            int j = k >> 7, b = k & 127;
            int i = (o + 25 + j) & 31;          // (o-7+j) mod 32
            int a = 7 - j;
            v = W[((i * BSZ + b) * ABI + a) * BSZ + c];
        } else {
            int r = k - 1024;
            v = L2[(o * BSZ + c) * LRK + r];
        }
        Wbt[idx] = f2bf(v);
    } else {
        int i2 = idx - totW;                    // < 64*4096
        L1b[i2] = f2bf(L1[i2]);
    }
}

// ---------------------------------------------------------------------------
// Kernel 2: one pass over x (f32): write x_bf16 and h = x @ L1^T (bf16).
// ---------------------------------------------------------------------------
__global__ __launch_bounds__(256) void gm_cast_h(
        const float* __restrict__ x, const u16* __restrict__ L1b,
        u16* __restrict__ xb, u16* __restrict__ hb) {
    __shared__ float red[4][4][256];
    int t = threadIdx.x;
    int w = t >> 6, lane = t & 63;
    int lr = lane & 15, lk = (lane >> 4) << 3;
    int rb = blockIdx.x * 16;
    int row = rb + lr;
    f32x4 acc[4];
#pragma unroll
    for (int ni = 0; ni < 4; ++ni) acc[ni] = (f32x4){0.f, 0.f, 0.f, 0.f};
    const int k_base = w * 1024;
    for (int ks = 0; ks < 32; ++ks) {
        int k0 = k_base + ks * 32 + lk;
        const float* xp = x + (size_t)row * INF + k0;
        f32x4 x0 = *reinterpret_cast<const f32x4*>(xp);
        f32x4 x1 = *reinterpret_cast<const f32x4*>(xp + 4);
        bf16x8 af;
        af[0] = (short)f2bf(x0[0]); af[1] = (short)f2bf(x0[1]);
        af[2] = (short)f2bf(x0[2]); af[3] = (short)f2bf(x0[3]);
        af[4] = (short)f2bf(x1[0]); af[5] = (short)f2bf(x1[1]);
        af[6] = (short)f2bf(x1[2]); af[7] = (short)f2bf(x1[3]);
        *reinterpret_cast<bf16x8*>(xb + (size_t)row * INF + k0) = af;
#pragma unroll
        for (int ni = 0; ni < 4; ++ni) {
            bf16x8 bv = *reinterpret_cast<const bf16x8*>(
                L1b + (size_t)(ni * 16 + lr) * INF + k0);
            acc[ni] = __builtin_amdgcn_mfma_f32_16x16x32_bf16(af, bv, acc[ni], 0, 0, 0);
        }
    }
#pragma unroll
    for (int ni = 0; ni < 4; ++ni)
#pragma unroll
        for (int j = 0; j < 4; ++j) red[w][ni][lane * 4 + j] = acc[ni][j];
    __syncthreads();
    if (t < 64) {
#pragma unroll
        for (int ni = 0; ni < 4; ++ni)
#pragma unroll
            for (int j = 0; j < 4; ++j) {
                float s = red[0][ni][lane * 4 + j] + red[1][ni][lane * 4 + j]
                        + red[2][ni][lane * 4 + j] + red[3][ni][lane * 4 + j];
                int r_ = rb + ((lane >> 4) << 2) + j;
                int c_ = ni * 16 + (lane & 15);
                hb[(size_t)r_ * LRK + c_] = f2bf(s);
            }
    }
}

// ---------------------------------------------------------------------------
// Kernel 3: main GEMM, pipelined. Tile 256x128, BK=64, 8 waves (4Mx2N).
// Double-buffered swizzled LDS, counted vmcnt(3), raw s_barrier, setprio.
// LDS layout: element (row,k) at row*128B + ((k>>3)^(row&7))*16B + (k&7)*2B.
// Staged via linear global_load_lds with pre-swizzled SOURCE address.
// ---------------------------------------------------------------------------
__global__ __launch_bounds__(512, 2) void gm_gemm(
        const u16* __restrict__ xb, const u16* __restrict__ hb,
        const u16* __restrict__ Wbt, float* __restrict__ out) {
    __shared__ u16 As[2][BM * BK];   // 2 x 32 KB
    __shared__ u16 Bs[2][BN * BK];   // 2 x 16 KB

    int bid = blockIdx.x;
    int swz = (bid & 7) * 128 + (bid >> 3);   // XCD-aware, 1024 % 8 == 0
    int o   = swz >> 5;                        // 4 consecutive o per XCD
    int mt  = swz & 31;
    int mbase = mt * BM;
    const u16* wb_o = Wbt + (size_t)o * (BSZ * KTOT);

    int t = threadIdx.x;
    // ---- staging geometry (thread t loads 16B; dest linear, src swizzled)
    int slot = t & 7, rb8 = t >> 3;                  // rb8: 0..63
    int ksst = (slot ^ (rb8 & 7)) << 3;              // swizzled k elem offset
    size_t a00 = (size_t)(mbase +   0 + rb8) * INF + ksst;
    size_t a01 = (size_t)(mbase +  64 + rb8) * INF + ksst;
    size_t a10 = (size_t)(mbase + 128 + rb8) * INF + ksst;
    size_t a11 = (size_t)(mbase + 192 + rb8) * INF + ksst;
    size_t h00 = (size_t)(mbase +   0 + rb8) * LRK + ksst;
    size_t h01 = (size_t)(mbase +  64 + rb8) * LRK + ksst;
    size_t h10 = (size_t)(mbase + 128 + rb8) * LRK + ksst;
    size_t h11 = (size_t)(mbase + 192 + rb8) * LRK + ksst;
    size_t b0  = (size_t)(rb8) * KTOT + ksst;
    size_t b1  = (size_t)(64 + rb8) * KTOT + ksst;
    int dA00 = (  0 + rb8) * BK + slot * 8;
    int dA01 = ( 64 + rb8) * BK + slot * 8;
    int dA10 = (128 + rb8) * BK + slot * 8;
    int dA11 = (192 + rb8) * BK + slot * 8;
    int dB0  = (rb8) * BK + slot * 8;
    int dB1  = (64 + rb8) * BK + slot * 8;
    int cb = (o + 25) * BSZ;                          // band start (mask later)

#define STAGE(T, SIDE, P) do {                                              \
    u16* As_ = &As[0][0] + (SIDE) * (BM * BK);                              \
    u16* Bs_ = &Bs[0][0] + (SIDE) * (BN * BK);                              \
    if ((T) < NKT - 1) {                                                    \
        int col_ = (cb + (T) * BK) & (INF - 1);                             \
        if ((P) == 0) {                                                     \
            async16(xb + a00 + col_, As_ + dA00);                           \
            async16(xb + a01 + col_, As_ + dA01);                           \
            async16(wb_o + b0 + (T) * BK, Bs_ + dB0);                       \
        } else {                                                            \
            async16(xb + a10 + col_, As_ + dA10);                           \
            async16(xb + a11 + col_, As_ + dA11);                           \
            async16(wb_o + b1 + (T) * BK, Bs_ + dB1);                       \
        }                                                                   \
    } else {                                                                \
        if ((P) == 0) {                                                     \
            async16(hb + h00, As_ + dA00);                                  \
            async16(hb + h01, As_ + dA01);                                  \
            async16(wb_o + b0 + (T) * BK, Bs_ + dB0);                       \
        } else {                                                            \
            async16(hb + h10, As_ + dA10);                                  \
            async16(hb + h11, As_ + dA11);                                  \
            async16(wb_o + b1 + (T) * BK, Bs_ + dB1);                       \
        }                                                                   \
    }                                                                       \
} while (0)

    // ---- fragment read geometry
    int lane = t & 63, w = t >> 6;
    int wr = w >> 1, wc = w & 1;                      // 4M x 2N waves
    int lr = lane & 15, g4 = lane >> 4;
    int ksw0 = ((g4) ^ (lr & 7)) << 4;                // kk=0 byte offset
    int ksw1 = ((4 + g4) ^ (lr & 7)) << 4;            // kk=1
    int ar0 = (wr * 64 +  0 + lr) * (BK * 2);
    int ar1 = (wr * 64 + 16 + lr) * (BK * 2);
    int ar2 = (wr * 64 + 32 + lr) * (BK * 2);
    int ar3 = (wr * 64 + 48 + lr) * (BK * 2);
    int br0 = (wc * 64 +  0 + lr) * (BK * 2);
    int br1 = (wc * 64 + 16 + lr) * (BK * 2);
    int br2 = (wc * 64 + 32 + lr) * (BK * 2);
    int br3 = (wc * 64 + 48 + lr) * (BK * 2);

    f32x4 acc00 = {0,0,0,0}, acc01 = {0,0,0,0}, acc02 = {0,0,0,0}, acc03 = {0,0,0,0};
    f32x4 acc10 = {0,0,0,0}, acc11 = {0,0,0,0}, acc12 = {0,0,0,0}, acc13 = {0,0,0,0};
    f32x4 acc20 = {0,0,0,0}, acc21 = {0,0,0,0}, acc22 = {0,0,0,0}, acc23 = {0,0,0,0};
    f32x4 acc30 = {0,0,0,0}, acc31 = {0,0,0,0}, acc32 = {0,0,0,0}, acc33 = {0,0,0,0};

#define COMPUTE(AB, BB, KS) do {                                            \
    bf16x8 af0 = *(const bf16x8*)((AB) + ar0 + (KS));                       \
    bf16x8 af1 = *(const bf16x8*)((AB) + ar1 + (KS));                       \
    bf16x8 af2 = *(const bf16x8*)((AB) + ar2 + (KS));                       \
    bf16x8 af3 = *(const bf16x8*)((AB) + ar3 + (KS));                       \
    bf16x8 bv0 = *(const bf16x8*)((BB) + br0 + (KS));                       \
    bf16x8 bv1 = *(const bf16x8*)((BB) + br1 + (KS));                       \
    bf16x8 bv2 = *(const bf16x8*)((BB) + br2 + (KS));                       \
    bf16x8 bv3 = *(const bf16x8*)((BB) + br3 + (KS));                       \
    __builtin_amdgcn_s_setprio(1);                                          \
    acc00 = __builtin_amdgcn_mfma_f32_16x16x32_bf16(af0, bv0, acc00, 0,0,0);\
    acc01 = __builtin_amdgcn_mfma_f32_16x16x32_bf16(af0, bv1, acc01, 0,0,0);\
    acc02 = __builtin_amdgcn_mfma_f32_16x16x32_bf16(af0, bv2, acc02, 0,0,0);\
    acc03 = __builtin_amdgcn_mfma_f32_16x16x32_bf16(af0, bv3, acc03, 0,0,0);\
    acc10 = __builtin_amdgcn_mfma_f32_16x16x32_bf16(af1, bv0, acc10, 0,0,0);\
    acc11 = __builtin_amdgcn_mfma_f32_16x16x32_bf16(af1, bv1, acc11, 0,0,0);\
    acc12 = __builtin_amdgcn_mfma_f32_16x16x32_bf16(af1, bv2, acc12, 0,0,0);\
    acc13 = __builtin_amdgcn_mfma_f32_16x16x32_bf16(af1, bv3, acc13, 0,0,0);\
    acc20 = __builtin_amdgcn_mfma_f32_16x16x32_bf16(af2, bv0, acc20, 0,0,0);\
    acc21 = __builtin_amdgcn_mfma_f32_16x16x32_bf16(af2, bv1, acc21, 0,0,0);\
    acc22 = __builtin_amdgcn_mfma_f32_16x16x32_bf16(af2, bv2, acc22, 0,0,0);\
    acc23 = __builtin_amdgcn_mfma_f32_16x16x32_bf16(af2, bv3, acc23, 0,0,0);\
    acc30 = __builtin_amdgcn_mfma_f32_16x16x32_bf16(af3, bv0, acc30, 0,0,0);\
    acc31 = __builtin_amdgcn_mfma_f32_16x16x32_bf16(af3, bv1, acc31, 0,0,0);\
    acc32 = __builtin_amdgcn_mfma_f32_16x16x32_bf16(af3, bv2, acc32, 0,0,0);\
    acc33 = __builtin_amdgcn_mfma_f32_16x16x32_bf16(af3, bv3, acc33, 0,0,0);\
    __builtin_amdgcn_s_setprio(0);                                          \
} while (0)

    // prologue: stage tile 0 fully into side 0
    STAGE(0, 0, 0);
    STAGE(0, 0, 1);

    for (int i = 0; i < NKT; ++i) {
        int s = i & 1;
        const char* Ab = (const char*)(&As[0][0] + s * (BM * BK));
        const char* Bb = (const char*)(&Bs[0][0] + s * (BN * BK));
        if (i < NKT - 1) {
            STAGE(i + 1, s ^ 1, 0);
            asm volatile("s_waitcnt vmcnt(3)" ::: "memory");
        } else {
            asm volatile("s_waitcnt vmcnt(0)" ::: "memory");
        }
        BAR();                       // tile i fully resident (all waves)
        COMPUTE(Ab, Bb, ksw0);
        BAR();
        if (i < NKT - 1) STAGE(i + 1, s ^ 1, 1);
        COMPUTE(Ab, Bb, ksw1);
        BAR();
    }

    // epilogue: C/D col=lane&15, row=(lane>>4)*4+j
    int orow = mbase + wr * 64 + (g4 << 2);
    int ocol = o * BSZ + wc * 64 + lr;
#define STORE(A, MI, NI) do {                                               \
    float* p_ = out + (size_t)(orow + (MI) * 16) * OUTF + ocol + (NI) * 16; \
    p_[0] = (A)[0]; p_[OUTF] = (A)[1];                                      \
    p_[2 * OUTF] = (A)[2]; p_[3 * OUTF] = (A)[3];                           \
} while (0)
    STORE(acc00, 0, 0); STORE(acc01, 0, 1); STORE(acc02, 0, 2); STORE(acc03, 0, 3);
    STORE(acc10, 1, 0); STORE(acc11, 1, 1); STORE(acc12, 1, 2); STORE(acc13, 1, 3);
    STORE(acc20, 2, 0); STORE(acc21, 2, 1); STORE(acc22, 2, 2); STORE(acc23, 2, 3);
    STORE(acc30, 3, 0); STORE(acc31, 3, 1); STORE(acc32, 3, 2); STORE(acc33, 3, 3);
#undef STAGE
#undef COMPUTE
#undef STORE
}

extern "C" void kernel_launch(void* const* d_in, const int* in_sizes, int n_in,
                              void* d_out, int out_size, void* d_ws, size_t ws_size,
                              hipStream_t stream) {
    const float* x  = (const float*)d_in[0];   // [8192][4096]
    const float* W  = (const float*)d_in[1];   // [4096][8][128]
    const float* L1 = (const float*)d_in[2];   // [64][4096]
    const float* L2 = (const float*)d_in[3];   // [4096][64]
    float* out = (float*)d_out;

    char* ws = (char*)d_ws;
    u16* xb  = (u16*)(ws);                       // 8192*4096*2 = 67108864
    u16* hb  = (u16*)(ws + 67108864);            // 8192*64*2   = 1048576
    u16* Wbt = (u16*)(ws + 68157440);            // 32*128*1088*2 = 8912896
    u16* L1b = (u16*)(ws + 77070336);            // 64*4096*2   = 524288

    gm_prep<<<dim3(18432), dim3(256), 0, stream>>>(W, L1, L2, Wbt, L1b);
    gm_cast_h<<<dim3(512), dim3(256), 0, stream>>>(x, L1b, xb, hb);
    gm_gemm<<<dim3(1024), dim3(512), 0, stream>>>(xb, hb, Wbt, out);
}

// Round 3
// 202.365 us; speedup vs baseline: 1.1971x; 1.1971x over previous
//
#include <hip/hip_runtime.h>
#include <stdint.h>

typedef unsigned short u16;
typedef short bf16x8 __attribute__((ext_vector_type(8)));
typedef float f32x4 __attribute__((ext_vector_type(4)));

#define NOB 32
#define ABI 8
#define BSZ 128
#define INF 4096
#define OUTF 4096
#define LRK 64
#define KT2 1280          // padded union K per o-pair: 1152 band + 64 lowrank + 64 zero
#define NST 16            // o-supertiles (pairs)

__device__ __forceinline__ u16 f2bf(float f) {
    uint32_t u = __float_as_uint(f);
    u += 0x7fffu + ((u >> 16) & 1u);
    return (u16)(u >> 16);
}

__device__ __forceinline__ void async16(const u16* g, u16* l) {
    __builtin_amdgcn_global_load_lds(
        (const __attribute__((address_space(1))) uint32_t*)g,
        (__attribute__((address_space(3))) uint32_t*)l, 16, 0, 0);
}

#define FENCE() asm volatile("" ::: "memory")

// ---------------------------------------------------------------------------
// Kernel 1: pack Wb2[os][c2(256)][k(1280)] bf16 + L1b.
// o = 2*os + (c2>>7), c = c2&127, rel = k - 128*(c2>>7).
// k<1152 & rel in [0,1024): j=rel>>7, b=rel&127, i=(o+25+j)&31, a=7-j
//   -> weight[((i*128+b)*8+a)*128+c];  k in [1152,1216): L2[(o*128+c)*64+(k-1152)]
// else 0.
// ---------------------------------------------------------------------------
__global__ __launch_bounds__(256) void gm_prep(
        const float* __restrict__ W, const float* __restrict__ L1,
        const float* __restrict__ L2,
        u16* __restrict__ Wb2, u16* __restrict__ L1b) {
    int idx = blockIdx.x * 256 + threadIdx.x;
    const int totW = NST * 256 * KT2;           // 5242880
    if (idx < totW) {
        int os  = idx / (256 * KT2);
        int rem = idx % (256 * KT2);
        int c2  = rem / KT2;
        int k   = rem % KT2;
        int hh  = c2 >> 7, c = c2 & 127;
        int o   = 2 * os + hh;
        int rel = k - (hh << 7);
        float v = 0.f;
        if (k < 1152) {
            if (rel >= 0 && rel < 1024) {
                int j = rel >> 7, b = rel & 127;
                int i = (o + 25 + j) & 31;
                int a = 7 - j;
                v = W[((i * BSZ + b) * ABI + a) * BSZ + c];
            }
        } else if (k < 1216) {
            v = L2[(o * BSZ + c) * LRK + (k - 1152)];
        }
        Wb2[idx] = f2bf(v);
    } else {
        int i2 = idx - totW;                    // < 64*4096
        L1b[i2] = f2bf(L1[i2]);
    }
}

// ---------------------------------------------------------------------------
// Kernel 2: one pass over x (f32): write x_bf16 and h = x @ L1^T (bf16).
// ---------------------------------------------------------------------------
__global__ __launch_bounds__(256) void gm_cast_h(
        const float* __restrict__ x, const u16* __restrict__ L1b,
        u16* __restrict__ xb, u16* __restrict__ hb) {
    __shared__ float red[4][4][256];
    int t = threadIdx.x;
    int w = t >> 6, lane = t & 63;
    int lr = lane & 15, lk = (lane >> 4) << 3;
    int rb = blockIdx.x * 16;
    int row = rb + lr;
    f32x4 acc[4];
#pragma unroll
    for (int ni = 0; ni < 4; ++ni) acc[ni] = (f32x4){0.f, 0.f, 0.f, 0.f};
    const int k_base = w * 1024;
    for (int ks = 0; ks < 32; ++ks) {
        int k0 = k_base + ks * 32 + lk;
        const float* xp = x + (size_t)row * INF + k0;
        f32x4 x0 = *reinterpret_cast<const f32x4*>(xp);
        f32x4 x1 = *reinterpret_cast<const f32x4*>(xp + 4);
        bf16x8 af;
        af[0] = (short)f2bf(x0[0]); af[1] = (short)f2bf(x0[1]);
        af[2] = (short)f2bf(x0[2]); af[3] = (short)f2bf(x0[3]);
        af[4] = (short)f2bf(x1[0]); af[5] = (short)f2bf(x1[1]);
        af[6] = (short)f2bf(x1[2]); af[7] = (short)f2bf(x1[3]);
        *reinterpret_cast<bf16x8*>(xb + (size_t)row * INF + k0) = af;
#pragma unroll
        for (int ni = 0; ni < 4; ++ni) {
            bf16x8 bv = *reinterpret_cast<const bf16x8*>(
                L1b + (size_t)(ni * 16 + lr) * INF + k0);
            acc[ni] = __builtin_amdgcn_mfma_f32_16x16x32_bf16(af, bv, acc[ni], 0, 0, 0);
        }
    }
#pragma unroll
    for (int ni = 0; ni < 4; ++ni)
#pragma unroll
        for (int j = 0; j < 4; ++j) red[w][ni][lane * 4 + j] = acc[ni][j];
    __syncthreads();
    if (t < 64) {
#pragma unroll
        for (int ni = 0; ni < 4; ++ni)
#pragma unroll
            for (int j = 0; j < 4; ++j) {
                float s = red[0][ni][lane * 4 + j] + red[1][ni][lane * 4 + j]
                        + red[2][ni][lane * 4 + j] + red[3][ni][lane * 4 + j];
                int r_ = rb + ((lane >> 4) << 2) + j;
                int c_ = ni * 16 + (lane & 15);
                hb[(size_t)r_ * LRK + c_] = f2bf(s);
            }
    }
}

// ---------------------------------------------------------------------------
// Kernel 3: 256x256 8-phase GEMM. 8 waves (2Mx4N), wave out 128x64 arranged
// as 2x2 quadrants of 64x32 so phase (MH,NH) reads exactly A-half MH and
// B-half NH. 20 K-tiles of 64. LDS 128 KB: [slot][half][128][64] x {A,B},
// XOR-swizzled k-slots (written via pre-swizzled global source, linear dest).
// Per phase: 12 ds_read_b128 | stage 1 half (2 gload_lds) | vmcnt(4) |
// s_barrier | lgkmcnt(0)+sched_barrier | setprio(1) 16 MFMA setprio(0).
// ---------------------------------------------------------------------------
__global__ __launch_bounds__(512) void gm_gemm(
        const u16* __restrict__ xb, const u16* __restrict__ hb,
        const u16* __restrict__ Wb2, float* __restrict__ out) {
    __shared__ u16 As[2][2][8192];   // [slot][half][128*64]  64 KB
    __shared__ u16 Bs[2][2][8192];   // 64 KB

    int mt = blockIdx.x;             // 0..31 (fast: rows)
    int os = blockIdx.y;             // 0..15 (slow: supertile col)
    int mbase = mt * 256;
    const u16* wb = Wb2 + (size_t)os * (256 * KT2);
    int cb0 = ((2 * os + 25) * BSZ) & (INF - 1);

    int t = threadIdx.x;
    int lane = t & 63, w = t >> 6;
    int wr = w >> 2, wc = w & 3;     // 2M x 4N
    int lr = lane & 15, g4 = lane >> 4;

    // staging geometry: thread t, loads l=0,1 -> row = (t>>3)+64l, slot = t&7
    int sl = t & 7, row0 = t >> 3;
    int swo = (sl ^ (row0 & 7)) << 3;             // swizzled k-elem offset
    const u16* xa  = xb + (size_t)(mbase + row0) * INF + swo;
    const u16* ha  = hb + (size_t)(mbase + row0) * LRK + swo;
    const u16* wba = wb + (size_t)row0 * KT2 + swo;
    u16* AsD = &As[0][0][0] + t * 8;
    u16* BsD = &Bs[0][0][0] + t * 8;

#define STAGE_A_(Tn, SD, H) do {                                            \
    u16* d_ = AsD + (SD) * 16384 + (H) * 8192;                              \
    if ((Tn) < 18) {                                                        \
        int colT_ = (cb0 + (Tn) * 64) & (INF - 1);                          \
        async16(xa + (size_t)((H) * 128) * INF + colT_, d_);                \
        async16(xa + (size_t)((H) * 128 + 64) * INF + colT_, d_ + 4096);    \
    } else {                                                                \
        async16(ha + (H) * 128 * LRK, d_);                                  \
        async16(ha + ((H) * 128 + 64) * LRK, d_ + 4096);                    \
    }                                                                       \
} while (0)
#define STAGE_B_(Tn, SD, H) do {                                            \
    u16* d_ = BsD + (SD) * 16384 + (H) * 8192;                              \
    async16(wba + (size_t)((H) * 128) * KT2 + (Tn) * 64, d_);               \
    async16(wba + (size_t)((H) * 128 + 64) * KT2 + (Tn) * 64, d_ + 4096);   \
} while (0)

    // fragment geometry
    const u16* Abase = &As[0][0][0];
    const u16* Bbase = &Bs[0][0][0];
    int arow = (wr * 64 + lr) * 64;               // + m*1024
    int brow = (wc * 32 + lr) * 64;               // + n*1024
    int ksw0 = ((g4) ^ (lr & 7)) << 3;
    int ksw1 = ((4 + g4) ^ (lr & 7)) << 3;

    f32x4 acc[2][2][4][2];
#pragma unroll
    for (int p = 0; p < 2; ++p)
#pragma unroll
        for (int q = 0; q < 2; ++q)
#pragma unroll
            for (int m = 0; m < 4; ++m)
#pragma unroll
                for (int n = 0; n < 2; ++n) acc[p][q][m][n] = (f32x4){0,0,0,0};

#define MFMA16(MH, NH)                                                       \
    __builtin_amdgcn_s_setprio(1);                                           \
    acc[MH][NH][0][0] = __builtin_amdgcn_mfma_f32_16x16x32_bf16(a0k0, b0k0, acc[MH][NH][0][0], 0,0,0); \
    acc[MH][NH][0][1] = __builtin_amdgcn_mfma_f32_16x16x32_bf16(a0k0, b1k0, acc[MH][NH][0][1], 0,0,0); \
    acc[MH][NH][1][0] = __builtin_amdgcn_mfma_f32_16x16x32_bf16(a1k0, b0k0, acc[MH][NH][1][0], 0,0,0); \
    acc[MH][NH][1][1] = __builtin_amdgcn_mfma_f32_16x16x32_bf16(a1k0, b1k0, acc[MH][NH][1][1], 0,0,0); \
    acc[MH][NH][2][0] = __builtin_amdgcn_mfma_f32_16x16x32_bf16(a2k0, b0k0, acc[MH][NH][2][0], 0,0,0); \
    acc[MH][NH][2][1] = __builtin_amdgcn_mfma_f32_16x16x32_bf16(a2k0, b1k0, acc[MH][NH][2][1], 0,0,0); \
    acc[MH][NH][3][0] = __builtin_amdgcn_mfma_f32_16x16x32_bf16(a3k0, b0k0, acc[MH][NH][3][0], 0,0,0); \
    acc[MH][NH][3][1] = __builtin_amdgcn_mfma_f32_16x16x32_bf16(a3k0, b1k0, acc[MH][NH][3][1], 0,0,0); \
    acc[MH][NH][0][0] = __builtin_amdgcn_mfma_f32_16x16x32_bf16(a0k1, b0k1, acc[MH][NH][0][0], 0,0,0); \
    acc[MH][NH][0][1] = __builtin_amdgcn_mfma_f32_16x16x32_bf16(a0k1, b1k1, acc[MH][NH][0][1], 0,0,0); \
    acc[MH][NH][1][0] = __builtin_amdgcn_mfma_f32_16x16x32_bf16(a1k1, b0k1, acc[MH][NH][1][0], 0,0,0); \
    acc[MH][NH][1][1] = __builtin_amdgcn_mfma_f32_16x16x32_bf16(a1k1, b1k1, acc[MH][NH][1][1], 0,0,0); \
    acc[MH][NH][2][0] = __builtin_amdgcn_mfma_f32_16x16x32_bf16(a2k1, b0k1, acc[MH][NH][2][0], 0,0,0); \
    acc[MH][NH][2][1] = __builtin_amdgcn_mfma_f32_16x16x32_bf16(a2k1, b1k1, acc[MH][NH][2][1], 0,0,0); \
    acc[MH][NH][3][0] = __builtin_amdgcn_mfma_f32_16x16x32_bf16(a3k1, b0k1, acc[MH][NH][3][0], 0,0,0); \
    acc[MH][NH][3][1] = __builtin_amdgcn_mfma_f32_16x16x32_bf16(a3k1, b1k1, acc[MH][NH][3][1], 0,0,0); \
    __builtin_amdgcn_s_setprio(0);

#define PHASE(S, MH, NH, STAGE_STMT, VMC) do {                               \
    const u16* Ab_ = Abase + (S) * 16384 + (MH) * 8192;                      \
    const u16* Bb_ = Bbase + (S) * 16384 + (NH) * 8192;                      \
    bf16x8 a0k0 = *(const bf16x8*)(Ab_ + arow + 0 * 1024 + ksw0);            \
    bf16x8 a1k0 = *(const bf16x8*)(Ab_ + arow + 1 * 1024 + ksw0);            \
    bf16x8 a2k0 = *(const bf16x8*)(Ab_ + arow + 2 * 1024 + ksw0);            \
    bf16x8 a3k0 = *(const bf16x8*)(Ab_ + arow + 3 * 1024 + ksw0);            \
    bf16x8 a0k1 = *(const bf16x8*)(Ab_ + arow + 0 * 1024 + ksw1);            \
    bf16x8 a1k1 = *(const bf16x8*)(Ab_ + arow + 1 * 1024 + ksw1);            \
    bf16x8 a2k1 = *(const bf16x8*)(Ab_ + arow + 2 * 1024 + ksw1);            \
    bf16x8 a3k1 = *(const bf16x8*)(Ab_ + arow + 3 * 1024 + ksw1);            \
    bf16x8 b0k0 = *(const bf16x8*)(Bb_ + brow + 0 * 1024 + ksw0);            \
    bf16x8 b1k0 = *(const bf16x8*)(Bb_ + brow + 1 * 1024 + ksw0);            \
    bf16x8 b0k1 = *(const bf16x8*)(Bb_ + brow + 0 * 1024 + ksw1);            \
    bf16x8 b1k1 = *(const bf16x8*)(Bb_ + brow + 1 * 1024 + ksw1);            \
    STAGE_STMT;                                                              \
    asm volatile("s_waitcnt vmcnt(" VMC ")" ::: "memory");                   \
    FENCE(); __builtin_amdgcn_s_barrier(); FENCE();                          \
    asm volatile("s_waitcnt lgkmcnt(0)" ::: "memory");                       \
    __builtin_amdgcn_sched_barrier(0);                                       \
    MFMA16(MH, NH)                                                           \
} while (0)

    // prologue: stage tile 0 into slot 0 (order B0,A0,B1,A1)
    STAGE_B_(0, 0, 0); STAGE_A_(0, 0, 0); STAGE_B_(0, 0, 1); STAGE_A_(0, 0, 1);
    asm volatile("s_waitcnt vmcnt(4)" ::: "memory");
    FENCE(); __builtin_amdgcn_s_barrier(); FENCE();

#pragma unroll 1
    for (int T = 0; T < 18; T += 2) {
        // group T (slot 0), stage T+1 -> slot 1
        PHASE(0, 0, 0, STAGE_B_(T + 1, 1, 0), "4");
        PHASE(0, 0, 1, STAGE_A_(T + 1, 1, 0), "4");
        PHASE(0, 1, 0, STAGE_B_(T + 1, 1, 1), "4");
        PHASE(0, 1, 1, STAGE_A_(T + 1, 1, 1), "4");
        // group T+1 (slot 1), stage T+2 -> slot 0
        PHASE(1, 0, 0, STAGE_B_(T + 2, 0, 0), "4");
        PHASE(1, 0, 1, STAGE_A_(T + 2, 0, 0), "4");
        PHASE(1, 1, 0, STAGE_B_(T + 2, 0, 1), "4");
        PHASE(1, 1, 1, STAGE_A_(T + 2, 0, 1), "4");
    }
    // group T=18 (slot 0), stage tile 19 -> slot 1
    PHASE(0, 0, 0, STAGE_B_(19, 1, 0), "4");
    PHASE(0, 0, 1, STAGE_A_(19, 1, 0), "4");
    PHASE(0, 1, 0, STAGE_B_(19, 1, 1), "4");
    PHASE(0, 1, 1, STAGE_A_(19, 1, 1), "4");
    // group T=19 (slot 1), no staging; drain
    PHASE(1, 0, 0, (void)0, "2");
    PHASE(1, 0, 1, (void)0, "0");
    PHASE(1, 1, 0, (void)0, "0");
    PHASE(1, 1, 1, (void)0, "0");

    // epilogue: C/D col=lane&15, row=(lane>>4)*4+j
    int orow = mbase + wr * 64 + (g4 << 2);
    int ocol = os * 256 + wc * 32 + lr;
#pragma unroll
    for (int mh = 0; mh < 2; ++mh)
#pragma unroll
        for (int nh = 0; nh < 2; ++nh)
#pragma unroll
            for (int m = 0; m < 4; ++m)
#pragma unroll
                for (int n = 0; n < 2; ++n) {
                    float* p_ = out + (size_t)(orow + mh * 128 + m * 16) * OUTF
                              + ocol + nh * 128 + n * 16;
#pragma unroll
                    for (int j = 0; j < 4; ++j)
                        p_[(size_t)j * OUTF] = acc[mh][nh][m][n][j];
                }
#undef STAGE_A_
#undef STAGE_B_
#undef PHASE
#undef MFMA16
}

extern "C" void kernel_launch(void* const* d_in, const int* in_sizes, int n_in,
                              void* d_out, int out_size, void* d_ws, size_t ws_size,
                              hipStream_t stream) {
    const float* x  = (const float*)d_in[0];   // [8192][4096]
    const float* W  = (const float*)d_in[1];   // [4096][8][128]
    const float* L1 = (const float*)d_in[2];   // [64][4096]
    const float* L2 = (const float*)d_in[3];   // [4096][64]
    float* out = (float*)d_out;

    char* ws = (char*)d_ws;
    u16* xb  = (u16*)(ws);                       // 67108864 B
    u16* hb  = (u16*)(ws + 67108864);            // 1048576 B
    u16* Wb2 = (u16*)(ws + 68157440);            // 16*256*1280*2 = 13107200 B
    u16* L1b = (u16*)(ws + 81264640);            // 524288 B

    gm_prep<<<dim3(21504), dim3(256), 0, stream>>>(W, L1, L2, Wb2, L1b);
    gm_cast_h<<<dim3(512), dim3(256), 0, stream>>>(x, L1b, xb, hb);
    gm_gemm<<<dim3(32, 16), dim3(512), 0, stream>>>(xb, hb, Wb2, out);
}